// Round 9
// baseline (94.264 us; speedup 1.0000x reference)
//
#include <hip/hip_runtime.h>
#include <hip/hip_bf16.h>
#include <stdint.h>

#define M_DIM 32
#define K_DIM 8192
#define N_DIM 8192
#define NGROUPS 64
#define KSPLIT 16
#define KPART (K_DIM / KSPLIT)     // 512 k-values per part
#define GPART (NGROUPS / KSPLIT)   // 4 groups per part
#define BN 128

typedef __attribute__((ext_vector_type(8))) short short8;   // 8 bf16 (4 VGPRs)
typedef __attribute__((ext_vector_type(4))) float floatx4;  // MFMA acc

#define AS1(p) ((const __attribute__((address_space(1))) void*)(p))
#define AS3(p) ((__attribute__((address_space(3))) void*)(p))

// ---------------------------------------------------------------------------
// Pre-kernel: A (fp32, 32x8192) -> Abf (bf16, octet-permuted [0,4,1,5,2,6,3,7])
// and R[m][g] = sum over group g of bf16-ROUNDED A (so the +128 offset in the
// fused dequant cancels EXACTLY against 136*R).  Also zeroes d_out.
// ---------------------------------------------------------------------------
__global__ void marlin_prep_kernel(const float* __restrict__ A,
                                   uint16_t* __restrict__ Abf,
                                   float* __restrict__ R,
                                   float4* __restrict__ out4) {
    const int m = blockIdx.x;
    const int qtr = blockIdx.y;
    const int t = threadIdx.x;
    const int octet = qtr * 256 + t;     // 0..1023
    const int k0 = octet * 8;

    {   // zero out: 32768 threads * 8 floats = 262144 = M*N
        const int gtid = (qtr * 32 + m) * 256 + t;
        const float4 z = make_float4(0.f, 0.f, 0.f, 0.f);
        out4[gtid * 2] = z;
        out4[gtid * 2 + 1] = z;
    }

    const float* a = A + m * K_DIM + k0;
    uint16_t b[8];
    float sum = 0.f;
#pragma unroll
    for (int j = 0; j < 8; j++) {
        union { __hip_bfloat16 h; uint16_t u; } cv;
        cv.h = __float2bfloat16(a[j]);   // round-to-nearest bf16
        b[j] = cv.u;
        sum += __bfloat162float(cv.h);   // sum of the ROUNDED values
    }
    // pack in permuted k-order [0,4,1,5,2,6,3,7] to match nibble-pair extract
    uint32_t w0 = (uint32_t)b[0] | ((uint32_t)b[4] << 16);
    uint32_t w1 = (uint32_t)b[1] | ((uint32_t)b[5] << 16);
    uint32_t w2 = (uint32_t)b[2] | ((uint32_t)b[6] << 16);
    uint32_t w3 = (uint32_t)b[3] | ((uint32_t)b[7] << 16);
    *(uint4*)(Abf + (size_t)m * K_DIM + k0) = make_uint4(w0, w1, w2, w3);

#pragma unroll
    for (int off = 1; off < 16; off <<= 1) sum += __shfl_xor(sum, off, 16);
    if ((t & 15) == 0) R[m * NGROUPS + qtr * 16 + (t >> 4)] = sum;
}

// ---------------------------------------------------------------------------
// Main kernel: grid (N/128, KSPLIT=16) x 512 threads = 1024 blocks = 4/CU.
// R8 post-mortem: ~27us regardless of ordering => bytes-bound: per-CU staged
// traffic 384 KB (A-tiles restaged 64 MB chip-wide) at ~6 B/cyc/CU.
// R9: BN 64->128 + KSPLIT 8->16 — same grid/occupancy, but each A-tile
// serves 2x the output cols: per-CU staged bytes -31% (264 KB), in-flight
// per CU +33% (64 KB), q staging now full 512-B row segments.  Each wave
// computes 1 mtile x 2 ntiles (2x MFMA, C=8 regs).  Direct-to-LDS
// global_load_lds width=16 dbuf, order = barrier -> stage(g+1) -> compute(g);
// XOR swizzles keep A ds_read_b128 / q ds_read_b32 at free 2-way aliasing.
// ---------------------------------------------------------------------------
__global__ __launch_bounds__(512, 4) void
MarlinQuantLinear_68556267979256_kernel(const int* __restrict__ qw,
                                        const float* __restrict__ scales,
                                        const float* __restrict__ bias,
                                        const uint16_t* __restrict__ Abf,
                                        const float* __restrict__ R,
                                        float* __restrict__ out) {
    __shared__ uint32_t qbuf[2][16 * 128];  // 8 KB per buf: 16 rows x 512 B
    __shared__ uint32_t abuf[2][32 * 64];   // 8 KB per buf: 32 rows x 256 B
    __shared__ float    r_lds[32 * 5];      // 136*R, padded stride 5

    const int bx = blockIdx.x;           // n-tile block (fastest)
    const int bz = blockIdx.y;           // k-split part
    const int nbase = bx * BN;
    const int kbase = bz * KPART;        // uint16 offset into an Abf row
    const int gbase = bz * GPART;
    const int qrow0 = bz * (KPART / 8);  // first packed qweight row (64/part)

    const int tid = threadIdx.x;
    const int w = tid >> 6;
    const int lane = tid & 63;
    const int quad = lane >> 4;
    const int l16 = lane & 15;
    const int mtile = w & 1;             // wave's m-tile
    const int nt0 = (w >> 1) * 2;        // wave's first of two n-tiles
    const int ncol0 = nbase + nt0 * 16 + l16;
    const int ncol1 = ncol0 + 16;
    const int arow = mtile * 16 + l16;   // this lane's A row for fragments

    // stage this part's R (prescaled by 136): 32m x 4g = 128 entries
    if (tid < 128) {
        const int mm = tid >> 2, gg = tid & 3;
        r_lds[mm * 5 + gg] = 136.0f * R[mm * NGROUPS + gbase + gg];
    }

    // scale prefetch: 2 cols x 4 groups, in flight behind the first stage
    const float* scol = scales + (size_t)gbase * N_DIM;
    float s0[GPART], s1[GPART];
#pragma unroll
    for (int g = 0; g < GPART; g++) {
        s0[g] = scol[g * N_DIM + ncol0];
        s1[g] = scol[g * N_DIM + ncol1];
    }

    // ---- staging maps (thread -> 16B chunk), swizzle on the GLOBAL side ----
    // A: row = tid>>4 (0..31), pos p = tid&15; LDS[row][p] gets global chunk
    // p ^ (row&15)  => fragment (t,quad) of row r sits at (t*4+quad)^(r&15)
    const int sra = tid >> 4, spa = tid & 15;
    const uint16_t* ga_base = Abf + (size_t)sra * K_DIM + kbase
                            + ((spa ^ (sra & 15)) << 3);       // chunk*8 bf16
    // q: row = tid>>5 (0..15), pos p = tid&31 (32 chunks = 512 B row);
    // LDS[row][chunk p] gets global chunk p ^ ((row&1)<<2)
    //   => dword (row,col) sits at LDS col ^ ((row&1)<<4)
    const int srq = tid >> 5, spq = tid & 31;
    const int* gq_base = qw + (size_t)(qrow0 + srq) * N_DIM + nbase
                       + ((spq * 4) ^ ((srq & 1) << 4));

    auto stage = [&](int g, int buf) {
        // A tile: 512 threads x 16B = 8 KB (8 wave-instructions)
        __builtin_amdgcn_global_load_lds(AS1(ga_base + g * 128),
                                         AS3(&abuf[buf][w * 256]), 16, 0, 0);
        // q tile: 512 threads x 16B = 8 KB (8 wave-instructions)
        __builtin_amdgcn_global_load_lds(AS1(gq_base + (size_t)g * 16 * N_DIM),
                                         AS3(&qbuf[buf][w * 256]), 16, 0, 0);
    };

    stage(0, 0);

    floatx4 C0 = {0.f, 0.f, 0.f, 0.f};
    floatx4 C1 = {0.f, 0.f, 0.f, 0.f};

#pragma unroll
    for (int g = 0; g < GPART; g++) {
        __syncthreads();                 // drains loads issued one phase ago
        if (g + 1 < GPART) stage(g + 1, (g + 1) & 1);

        const uint32_t* qb = qbuf[g & 1];
        const uint32_t* ab = abuf[g & 1];
        floatx4 acc0 = {0.f, 0.f, 0.f, 0.f};
        floatx4 acc1 = {0.f, 0.f, 0.f, 0.f};
#pragma unroll
        for (int t = 0; t < 4; t++) {
            const int qrow = (t * 4 + quad) * 128;
            const uint32_t qA =
                qb[qrow + ((nt0 * 16 + l16) ^ ((quad & 1) << 4))];
            const uint32_t qB =
                qb[qrow + (((nt0 + 1) * 16 + l16) ^ ((quad & 1) << 4))];
            const short8 fa = *(const short8*)
                &ab[arow * 64 + (((t * 4 + quad) ^ (arow & 15)) << 2)];
            union { uint32_t u[4]; short8 v; } fb;
            fb.u[0] = ( qA        & 0x000F000Fu) | 0x43004300u;  // k0,k4
            fb.u[1] = ((qA >> 4)  & 0x000F000Fu) | 0x43004300u;  // k1,k5
            fb.u[2] = ((qA >> 8)  & 0x000F000Fu) | 0x43004300u;  // k2,k6
            fb.u[3] = ((qA >> 12) & 0x000F000Fu) | 0x43004300u;  // k3,k7
            acc0 = __builtin_amdgcn_mfma_f32_16x16x32_bf16(fa, fb.v, acc0, 0, 0, 0);
            fb.u[0] = ( qB        & 0x000F000Fu) | 0x43004300u;
            fb.u[1] = ((qB >> 4)  & 0x000F000Fu) | 0x43004300u;
            fb.u[2] = ((qB >> 8)  & 0x000F000Fu) | 0x43004300u;
            fb.u[3] = ((qB >> 12) & 0x000F000Fu) | 0x43004300u;
            acc1 = __builtin_amdgcn_mfma_f32_16x16x32_bf16(fa, fb.v, acc1, 0, 0, 0);
        }
#pragma unroll
        for (int r = 0; r < 4; r++) {
            // acc row is global m = mtile*16 + quad*4 + r; r_lds holds 136*R
            const float Rv = r_lds[(mtile * 16 + quad * 4 + r) * 5 + g];
            C0[r] = fmaf(s0[g], acc0[r] - Rv, C0[r]);
            C1[r] = fmaf(s1[g], acc1[r] - Rv, C1[r]);
        }
    }

    const float bv0 = (bz == 0) ? bias[ncol0] : 0.0f;
    const float bv1 = (bz == 0) ? bias[ncol1] : 0.0f;
#pragma unroll
    for (int r = 0; r < 4; r++) {
        const int m = mtile * 16 + quad * 4 + r;   // C/D row = quad*4 + reg
        atomicAdd(&out[(size_t)m * N_DIM + ncol0], C0[r] + bv0);
        atomicAdd(&out[(size_t)m * N_DIM + ncol1], C1[r] + bv1);
    }
}

extern "C" void kernel_launch(void* const* d_in, const int* in_sizes, int n_in,
                              void* d_out, int out_size, void* d_ws, size_t ws_size,
                              hipStream_t stream) {
    const float* A      = (const float*)d_in[0];
    const int*   qw     = (const int*)d_in[1];
    const float* scales = (const float*)d_in[2];
    const float* bias   = (const float*)d_in[3];
    float* out = (float*)d_out;

    uint16_t* Abf = (uint16_t*)d_ws;                                   // 512 KB
    float*    R   = (float*)((char*)d_ws + (size_t)M_DIM * K_DIM * 2); //   8 KB

    marlin_prep_kernel<<<dim3(M_DIM, 4), 256, 0, stream>>>(A, Abf, R, (float4*)out);
    MarlinQuantLinear_68556267979256_kernel<<<dim3(N_DIM / BN, KSPLIT), 512, 0, stream>>>(
        qw, scales, bias, Abf, R, out);
}